// Round 12
// baseline (589.542 us; speedup 1.0000x reference)
//
#include <hip/hip_runtime.h>
#include <hip/hip_cooperative_groups.h>
#include <math.h>
#include <stdint.h>

namespace cg = cooperative_groups;

#define NIMG   8
#define NA     30000      // H*W*A = 100*100*3
#define PRE_N  2000
#define POST_N 1000
#define NMS_TH 0.7f
#define DCLIP  4.135166556742356f   // log(1000/16)
#define IMGF   1600.0f
#define IMGM1  1599.0f
#define CAND_MAX 4096
#define NBLK   256
#define NTHR   512

// ---------------------------------------------------------------------------
// Verified inline-asm scan macros (R8): 64-slot VGPR ring, pure-SALU chain,
// early-exit at kept=1000.
// ---------------------------------------------------------------------------
#define SL(n,b) \
    "global_load_dword v" #n ", %[voff], %[sbase]\n\t" \
    "v_add_u32 %[voff], 0x100, %[voff]\n\t"

#define SS(n,b) \
    "s_waitcnt vmcnt(63)\n\t" \
    "v_readlane_b32 %[t], v" #n ", %[lw]\n\t" \
    "s_bitcmp1_b32 %[win], " #b "\n\t" \
    "s_cselect_b32 %[m], 0, -1\n\t" \
    "s_sub_i32 %[kept], %[kept], %[m]\n\t" \
    "s_and_b32 %[t], %[t], %[m]\n\t" \
    "s_or_b32 %[win], %[win], %[t]\n\t" \
    "v_and_b32 v" #n ", %[m], v" #n "\n\t" \
    "v_or_b32 %[rem], %[rem], v" #n "\n\t" \
    "global_load_dword v" #n ", %[voff], %[sbase]\n\t" \
    "v_add_u32 %[voff], 0x100, %[voff]\n\t"

#define SN(n,b,w) \
    "s_waitcnt vmcnt(" #w ")\n\t" \
    "v_readlane_b32 %[t], v" #n ", %[lw]\n\t" \
    "s_bitcmp1_b32 %[win], " #b "\n\t" \
    "s_cselect_b32 %[m], 0, -1\n\t" \
    "s_sub_i32 %[kept], %[kept], %[m]\n\t" \
    "s_and_b32 %[t], %[t], %[m]\n\t" \
    "s_or_b32 %[win], %[win], %[t]\n\t" \
    "v_and_b32 v" #n ", %[m], v" #n "\n\t" \
    "v_or_b32 %[rem], %[rem], v" #n "\n\t"

#define SWIN \
    "s_add_u32 %[lw], %[lw], 1\n\t" \
    "v_readlane_b32 %[t], %[rem], %[lw]\n\t" \
    "s_mov_b32 %[win], %[t]\n\t"

#define ROW_A(M) M(64,0) M(65,1) M(66,2) M(67,3) M(68,4) M(69,5) M(70,6) M(71,7) \
    M(72,8) M(73,9) M(74,10) M(75,11) M(76,12) M(77,13) M(78,14) M(79,15) \
    M(80,16) M(81,17) M(82,18) M(83,19) M(84,20) M(85,21) M(86,22) M(87,23) \
    M(88,24) M(89,25) M(90,26) M(91,27) M(92,28) M(93,29) M(94,30) M(95,31)
#define ROW_B(M) M(96,0) M(97,1) M(98,2) M(99,3) M(100,4) M(101,5) M(102,6) M(103,7) \
    M(104,8) M(105,9) M(106,10) M(107,11) M(108,12) M(109,13) M(110,14) M(111,15) \
    M(112,16) M(113,17) M(114,18) M(115,19) M(116,20) M(117,21) M(118,22) M(119,23) \
    M(120,24) M(121,25) M(122,26) M(123,27) M(124,28) M(125,29) M(126,30) M(127,31)

// ---------------------------------------------------------------------------
// ONE cooperative kernel: all phases, grid.sync() between them.
// ---------------------------------------------------------------------------
__global__ __launch_bounds__(NTHR) void rpn_mega(
    const float* __restrict__ obj, const float* __restrict__ breg,
    float* __restrict__ wsBoxes, float* __restrict__ wsScores,
    int* __restrict__ wsValid, uint64_t* __restrict__ candBuf,
    unsigned int* __restrict__ candCnt, unsigned int* __restrict__ bstarArr,
    unsigned int* __restrict__ gHist, uint64_t* __restrict__ mask,
    float* __restrict__ out)
{
    cg::grid_group grid = cg::this_grid();
    const int blk  = blockIdx.x;
    const int tid  = threadIdx.x;
    const int lane = tid & 63;
    const int wid  = tid >> 6;
    const int g    = blk * NTHR + tid;

    __shared__ uint64_t sTile[64 * 33];           // P5 mask staging (16.9 KB)
    __shared__ int      sScan[NTHR];              // P6 prefix scan
    __shared__ unsigned int sWsum[8];             // P2
    __shared__ unsigned int sScal[4];             // P2
    __shared__ __align__(8) unsigned char sInvb[256];  // P6
    __shared__ unsigned int sKeep[64];            // P6

    // ---- P0: zero hist + counters ----
    if (g < NIMG * 4096) gHist[g] = 0u;
    if (g < NIMG) { candCnt[g] = 0u; bstarArr[g] = 0u; }
    grid.sync();

    // ---- P1: global-atomic histogram over sortable keys ----
    for (int i = g; i < NIMG * NA; i += NBLK * NTHR) {
        const int n = i / NA;
        unsigned int u = __float_as_uint(obj[i]);
        unsigned int k = (u & 0x80000000u) ? ~u : (u | 0x80000000u);
        atomicAdd(&gHist[n * 4096 + (k >> 20)], 1u);
    }
    grid.sync();

    // ---- P2: boundary bin b* per image (blocks 0..7), verified suffix logic ----
    if (blk < NIMG) {
        const int n = blk;
        unsigned int cb8[8], p = 0;
        for (int q = 0; q < 8; ++q) { cb8[q] = gHist[n * 4096 + tid * 8 + q]; p += cb8[q]; }
        unsigned int s = p;
        #pragma unroll
        for (int off = 1; off < 64; off <<= 1) {
            unsigned int v = __shfl_down(s, off);
            if (lane + off < 64) s += v;
        }
        if (lane == 0) sWsum[wid] = s;
        __syncthreads();
        unsigned int wafter = 0;
        for (int w = wid + 1; w < 8; ++w) wafter += sWsum[w];
        unsigned int suf = (s - p) + wafter;   // suffix-exclusive after my 8 bins
        for (int q = 7; q >= 0; --q) {
            unsigned int Sq = suf + cb8[q];
            if (Sq >= PRE_N && suf < PRE_N) sScal[0] = (unsigned int)(tid * 8 + q);
            suf = Sq;
        }
        __syncthreads();
        if (tid == 0) bstarArr[n] = sScal[0];
    }
    grid.sync();

    // ---- P3: compact all candidates (bin >= b*), order-free ----
    for (int i = g; i < NIMG * NA; i += NBLK * NTHR) {
        const int n = i / NA;
        const int j = i - n * NA;
        unsigned int u = __float_as_uint(obj[i]);
        unsigned int k = (u & 0x80000000u) ? ~u : (u | 0x80000000u);
        if ((k >> 20) >= bstarArr[n]) {
            int a = j / 10000, t = j - a * 10000;
            uint64_t key = (((uint64_t)(~k)) << 32) | (unsigned int)(t * 3 + a);
            unsigned int pos = atomicAdd(&candCnt[n], 1u);
            if (pos < CAND_MAX) candBuf[n * CAND_MAX + pos] = key;
        }
    }
    grid.sync();

    // ---- P4: wave-wide rank-by-counting + decode (verified R9) ----
    {
        const int gw = blk * 8 + wid;
        if (gw < NIMG * 64) {
            const int n = gw >> 6, tile = gw & 63;
            const int C = min((int)candCnt[n], CAND_MAX);
            if (tile * 64 < C) {
                const uint64_t* cb = candBuf + n * CAND_MAX;
                const int my = tile * 64 + lane;
                const uint64_t km = (my < C) ? cb[my] : ~0ull;
                unsigned int rank = 0;
                const int nch = (C + 63) >> 6;
                for (int ch = 0; ch < nch; ++ch) {
                    const int j = ch * 64 + lane;
                    uint64_t ck = (j < C) ? cb[j] : ~0ull;
                    unsigned int clo = (unsigned int)ck, chi = (unsigned int)(ck >> 32);
                    #pragma unroll
                    for (int c2 = 0; c2 < 64; ++c2) {
                        unsigned int lo = (unsigned int)__builtin_amdgcn_readlane((int)clo, c2);
                        unsigned int hi = (unsigned int)__builtin_amdgcn_readlane((int)chi, c2);
                        uint64_t kc = ((uint64_t)hi << 32) | lo;
                        rank += (kc < km) ? 1u : 0u;
                    }
                }
                if (my < C && rank < PRE_N) {
                    unsigned int idx = (unsigned int)km;
                    unsigned int k   = ~((unsigned int)(km >> 32));
                    unsigned int u   = (k & 0x80000000u) ? (k & 0x7fffffffu) : ~k;
                    float logit = __uint_as_float(u);
                    float score = 1.0f / (1.0f + expf(-logit));

                    int a = idx % 3, t = idx / 3, w = t % 100, h = t / 100;
                    const float* bp = breg + n*120000 + (a*4)*10000 + t;
                    float dx = bp[0], dy = bp[10000], dw = bp[20000], dh = bp[30000];

                    float half = (a == 0) ? 32.0f : ((a == 1) ? 64.0f : 128.0f);
                    float cx = w * 16.0f + 8.0f, cy = h * 16.0f + 8.0f;
                    float x1 = cx - half, y1 = cy - half, x2 = cx + half, y2 = cy + half;
                    float wd = x2 - x1 + 1.0f, hg = y2 - y1 + 1.0f;
                    float cxr = x1 + 0.5f * wd, cyr = y1 + 0.5f * hg;
                    dw = fminf(dw, DCLIP); dh = fminf(dh, DCLIP);
                    float pcx = dx * wd + cxr, pcy = dy * hg + cyr;
                    float pw = expf(dw) * wd, ph = expf(dh) * hg;
                    float px1 = pcx - 0.5f * pw, py1 = pcy - 0.5f * ph;
                    float px2 = pcx + 0.5f * pw - 1.0f, py2 = pcy + 0.5f * ph - 1.0f;
                    px1 = fminf(fmaxf(px1, 0.0f), IMGM1);
                    px2 = fminf(fmaxf(px2, 0.0f), IMGM1);
                    py1 = fminf(fmaxf(py1, 0.0f), IMGM1);
                    py2 = fminf(fmaxf(py2, 0.0f), IMGM1);
                    float wss = px2 - px1 + 1.0f, hss = py2 - py1 + 1.0f;
                    float xc = px1 + wss * 0.5f, yc = py1 + hss * 0.5f;
                    int valid = (wss >= 0.0f) && (hss >= 0.0f) && (xc < IMGF) && (yc < IMGF);

                    ((float4*)wsBoxes)[n * PRE_N + (int)rank] = make_float4(px1, py1, px2, py2);
                    wsScores[n * PRE_N + (int)rank] = score;
                    wsValid [n * PRE_N + (int)rank] = valid;
                }
            }
        }
    }
    grid.sync();

    // ---- P5: suppression bit-matrix (verified R11: div-free, LDS-staged store) ----
    {
        const int n   = blk >> 5;
        const int i_t = blk & 31;

        for (int idx = tid; idx < 64 * 33; idx += NTHR) sTile[idx] = 0ull;
        __syncthreads();

        const int r = i_t * 64 + lane;
        float4 rb = (r < PRE_N) ? ((const float4*)wsBoxes)[n * PRE_N + r]
                                : make_float4(0.f, 0.f, 0.f, 0.f);
        float ra = (rb.z - rb.x + 1.0f) * (rb.w - rb.y + 1.0f);

        for (int j_t = i_t + wid; j_t < 32; j_t += 8) {
            const int j = j_t * 64 + lane;
            float4 cbx = (j < PRE_N) ? ((const float4*)wsBoxes)[n * PRE_N + j]
                                     : make_float4(3e30f, 3e30f, 3e30f, 3e30f);
            float ca = (cbx.z - cbx.x + 1.0f) * (cbx.w - cbx.y + 1.0f);
            const uint64_t jmask = (j_t == 31) ? 0xFFFFull : ~0ull;
            const bool diag = (j_t == i_t);
            uint64_t myword = 0ull;

            #pragma unroll
            for (int c2 = 0; c2 < 64; ++c2) {
                float rx1 = __int_as_float(__builtin_amdgcn_readlane(__float_as_int(rb.x), c2));
                float ry1 = __int_as_float(__builtin_amdgcn_readlane(__float_as_int(rb.y), c2));
                float rx2 = __int_as_float(__builtin_amdgcn_readlane(__float_as_int(rb.z), c2));
                float ry2 = __int_as_float(__builtin_amdgcn_readlane(__float_as_int(rb.w), c2));
                float rar = __int_as_float(__builtin_amdgcn_readlane(__float_as_int(ra), c2));
                float xx1 = fmaxf(rx1, cbx.x), yy1 = fmaxf(ry1, cbx.y);
                float xx2 = fminf(rx2, cbx.z), yy2 = fminf(ry2, cbx.w);
                float ww = fmaxf(xx2 - xx1 + 1.0f, 0.0f);
                float hh = fmaxf(yy2 - yy1 + 1.0f, 0.0f);
                float inter = ww * hh;
                float denom = rar + ca - inter;
                unsigned long long bits = __ballot(inter > NMS_TH * denom) & jmask;
                if (diag) bits &= (c2 == 63) ? 0ull : ((~0ull) << (c2 + 1));
                if (lane == c2) myword = bits;
            }
            sTile[lane * 33 + j_t] = myword;
        }
        __syncthreads();

        uint64_t* mrow = mask + ((size_t)n * PRE_N + (size_t)i_t * 64) * 32;
        const int cmax = (i_t == 31) ? 16 : 64;
        for (int idx = tid; idx < cmax * 32; idx += NTHR) {
            const int rr = idx >> 5, w = idx & 31;
            mrow[idx] = sTile[rr * 33 + w];
        }
    }
    grid.sync();

    // ---- P6: serial greedy scan + rank-compact output (blocks 0..7) ----
    if (blk < NIMG) {
        const int n = blk;

        if (tid < 256) {
            unsigned int byte = 0xFFu;
            if (tid < PRE_N / 8) {
                byte = 0u;
                for (int q = 0; q < 8; ++q)
                    byte |= (wsValid[n * PRE_N + tid * 8 + q] ? 0u : 1u) << q;
            }
            sInvb[tid] = (unsigned char)byte;
        }
        __syncthreads();

        if (tid < 64) {
            unsigned int rem = ((const unsigned int*)sInvb)[tid];
            unsigned long long sbase =
                (unsigned long long)(const void*)(mask + (size_t)n * PRE_N * 32);
            unsigned int voff = (unsigned int)(tid * 4);
            int win_, m_, t_, lw_, kept_, cnt_;

            asm volatile(
                "s_waitcnt vmcnt(0) lgkmcnt(0)\n\t"
                "s_mov_b32 %[kept], 0\n\t"
                "s_mov_b32 %[lw], 0\n\t"
                ROW_A(SL) ROW_B(SL)
                "v_readlane_b32 %[t], %[rem], %[lw]\n\t"
                "s_mov_b32 %[win], %[t]\n\t"
                "s_mov_b32 %[cnt], 30\n\t"
                "Lnms_%=:\n\t"
                ROW_A(SS)
                SWIN
                ROW_B(SS)
                SWIN
                "s_cmp_ge_i32 %[kept], 0x3e8\n\t"
                "s_cbranch_scc1 Lend_%=\n\t"
                "s_sub_u32 %[cnt], %[cnt], 1\n\t"
                "s_cmp_lg_u32 %[cnt], 0\n\t"
                "s_cbranch_scc1 Lnms_%=\n\t"
                SS(64,0) SS(65,1) SS(66,2) SS(67,3) SS(68,4) SS(69,5) SS(70,6) SS(71,7)
                SS(72,8) SS(73,9) SS(74,10) SS(75,11) SS(76,12) SS(77,13) SS(78,14) SS(79,15)
                SN(80,16,63) SN(81,17,62) SN(82,18,61) SN(83,19,60)
                SN(84,20,59) SN(85,21,58) SN(86,22,57) SN(87,23,56)
                SN(88,24,55) SN(89,25,54) SN(90,26,53) SN(91,27,52)
                SN(92,28,51) SN(93,29,50) SN(94,30,49) SN(95,31,48)
                SWIN
                SN(96,0,47) SN(97,1,46) SN(98,2,45) SN(99,3,44)
                SN(100,4,43) SN(101,5,42) SN(102,6,41) SN(103,7,40)
                SN(104,8,39) SN(105,9,38) SN(106,10,37) SN(107,11,36)
                SN(108,12,35) SN(109,13,34) SN(110,14,33) SN(111,15,32)
                SN(112,16,31) SN(113,17,30) SN(114,18,29) SN(115,19,28)
                SN(116,20,27) SN(117,21,26) SN(118,22,25) SN(119,23,24)
                SN(120,24,23) SN(121,25,22) SN(122,26,21) SN(123,27,20)
                SN(124,28,19) SN(125,29,18) SN(126,30,17) SN(127,31,16)
                SWIN
                SN(64,0,15) SN(65,1,14) SN(66,2,13) SN(67,3,12)
                SN(68,4,11) SN(69,5,10) SN(70,6,9) SN(71,7,8)
                SN(72,8,7) SN(73,9,6) SN(74,10,5) SN(75,11,4)
                SN(76,12,3) SN(77,13,2) SN(78,14,1) SN(79,15,0)
                "Lend_%=:\n\t"
                "s_waitcnt vmcnt(0)\n\t"
                : [rem]"+v"(rem), [voff]"+v"(voff),
                  [win]"=&s"(win_), [m]"=&s"(m_), [t]"=&s"(t_),
                  [lw]"=&s"(lw_), [kept]"=&s"(kept_), [cnt]"=&s"(cnt_)
                : [sbase]"s"(sbase)
                : "scc", "vcc", "memory",
                  "v64","v65","v66","v67","v68","v69","v70","v71",
                  "v72","v73","v74","v75","v76","v77","v78","v79",
                  "v80","v81","v82","v83","v84","v85","v86","v87",
                  "v88","v89","v90","v91","v92","v93","v94","v95",
                  "v96","v97","v98","v99","v100","v101","v102","v103",
                  "v104","v105","v106","v107","v108","v109","v110","v111",
                  "v112","v113","v114","v115","v116","v117","v118","v119",
                  "v120","v121","v122","v123","v124","v125","v126","v127");

            sKeep[tid] = ~rem;
        }
        __syncthreads();

        // prefix scan of keep flags, 4 per thread over 512 threads
        int cf[4]; const int base4 = tid * 4;
        int lsum = 0;
        for (int q = 0; q < 4; ++q) {
            const int i = base4 + q;
            cf[q] = (i < PRE_N) ? (int)((sKeep[i >> 5] >> (i & 31)) & 1u) : 0;
            lsum += cf[q];
        }
        sScan[tid] = lsum;
        __syncthreads();
        for (int off = 1; off < NTHR; off <<= 1) {
            int v = (tid >= off) ? sScan[tid - off] : 0;
            __syncthreads();
            sScan[tid] += v;
            __syncthreads();
        }
        const int excl  = sScan[tid] - lsum;
        const int total = sScan[NTHR - 1];

        float* ob  = out + n * POST_N * 4;
        float* osc = out + NIMG * POST_N * 4 + n * POST_N;
        float* ovd = out + NIMG * POST_N * 5 + n * POST_N;

        for (int i = tid; i < POST_N * 4; i += NTHR) ob[i] = 0.0f;
        for (int i = tid; i < POST_N; i += NTHR) osc[i] = 0.0f;
        const int lim = min(total, POST_N);
        for (int i = tid; i < POST_N; i += NTHR) ovd[i] = (i < lim) ? 1.0f : 0.0f;
        __syncthreads();

        int run = excl;
        for (int q = 0; q < 4; ++q) {
            const int i = base4 + q;
            if (i < PRE_N && cf[q]) {
                if (run < POST_N) {
                    float4 b = ((const float4*)wsBoxes)[n * PRE_N + i];
                    ob[run * 4 + 0] = b.x;
                    ob[run * 4 + 1] = b.y;
                    ob[run * 4 + 2] = b.z;
                    ob[run * 4 + 3] = b.w;
                    osc[run] = wsScores[n * PRE_N + i];
                }
                run++;
            }
        }
    }
}

extern "C" void kernel_launch(void* const* d_in, const int* in_sizes, int n_in,
                              void* d_out, int out_size, void* d_ws, size_t ws_size,
                              hipStream_t stream) {
    const float* obj  = (const float*)d_in[0];
    const float* breg = (const float*)d_in[1];
    // d_in[2] anchors unused (computed inline, exact in f32)
    float* ws        = (float*)d_ws;
    float* wsBoxes   = ws;                      // 64000 floats
    float* wsScores  = ws + 64000;              // 16000 floats
    int*   wsValid   = (int*)(ws + 80000);      // 16000 ints
    uint64_t* wsMask = (uint64_t*)(ws + 96000); // 8*2000*32 u64 = 4.096 MB
    uint64_t* candBuf = wsMask;                 // alias: dead before P5 writes mask
    unsigned int* gHist =
        (unsigned int*)((char*)wsMask + (size_t)NIMG * PRE_N * 32 * 8);  // 128 KB
    unsigned int* candCnt  = gHist + NIMG * 4096;   // 8 u32
    unsigned int* bstarArr = candCnt + NIMG;        // 8 u32
    float* outp = (float*)d_out;

    void* args[] = {
        (void*)&obj, (void*)&breg, (void*)&wsBoxes, (void*)&wsScores,
        (void*)&wsValid, (void*)&candBuf, (void*)&candCnt, (void*)&bstarArr,
        (void*)&gHist, (void*)&wsMask, (void*)&outp
    };
    hipLaunchCooperativeKernel((const void*)rpn_mega, dim3(NBLK), dim3(NTHR),
                               args, 0, stream);
}

// Round 13
// 190.878 us; speedup vs baseline: 3.0886x; 3.0886x over previous
//
#include <hip/hip_runtime.h>
#include <math.h>
#include <stdint.h>

#define NIMG   8
#define NA     30000      // H*W*A = 100*100*3
#define PRE_N  2000
#define POST_N 1000
#define NMS_TH 0.7f
#define DCLIP  4.135166556742356f   // log(1000/16)
#define IMGF   1600.0f
#define IMGM1  1599.0f
#define CAND_MAX 4096

// ws layout: boxes [8][2000][4] f32 @0, scores @64000, valid(int) @80000,
// mask(u64 [8][2000][32]) @96000 floats (byte 384000, 4.096 MB),
// done[8] u32 AFTER mask (byte 4480000) — must not alias mask.
// candBuf (u64 [8][4096]) + candCnt alias the START of the mask region
// (dead before nms_mask_scan overwrites it; same stream => safe).

// ---------------------------------------------------------------------------
// Kernel A (verified R11 + done[] zeroing): histogram + boundary bin + compact.
// ---------------------------------------------------------------------------
__global__ __launch_bounds__(1024) void hist_compact(
    const float* __restrict__ obj,
    uint64_t* __restrict__ candBuf, unsigned int* __restrict__ candCnt,
    unsigned int* __restrict__ doneArr)
{
    const int n    = blockIdx.x;
    const int tid  = threadIdx.x;
    const int lane = tid & 63;
    const int wid  = tid >> 6;

    __shared__ unsigned int hist[4096];
    __shared__ unsigned int wsum[16];
    __shared__ unsigned int scal[4];

    for (int b = tid; b < 4096; b += 1024) hist[b] = 0u;
    if (tid < 4) scal[tid] = 0u;
    if (tid == 0) doneArr[n] = 0u;
    __syncthreads();

    const float* objn = obj + n * NA;

    for (int j = tid; j < NA; j += 1024) {
        unsigned int u = __float_as_uint(objn[j]);
        unsigned int k = (u & 0x80000000u) ? ~u : (u | 0x80000000u);
        atomicAdd(&hist[k >> 20], 1u);
    }
    __syncthreads();

    unsigned int c0 = hist[tid*4+0], c1 = hist[tid*4+1],
                 c2 = hist[tid*4+2], c3 = hist[tid*4+3];
    unsigned int p = c0 + c1 + c2 + c3;
    unsigned int s = p;
    #pragma unroll
    for (int off = 1; off < 64; off <<= 1) {
        unsigned int v = __shfl_down(s, off);
        if (lane + off < 64) s += v;
    }
    if (lane == 0) wsum[wid] = s;
    __syncthreads();
    unsigned int wafter = 0;
    for (int w = wid + 1; w < 16; ++w) wafter += wsum[w];
    unsigned int after = (s - p) + wafter;
    {
        unsigned int S3 = after + c3;
        unsigned int S2 = S3 + c2;
        unsigned int S1 = S2 + c1;
        unsigned int S0 = S1 + c0;
        if (S3 >= PRE_N && after < PRE_N) { scal[2] = tid*4+3; }
        if (S2 >= PRE_N && S3    < PRE_N) { scal[2] = tid*4+2; }
        if (S1 >= PRE_N && S2    < PRE_N) { scal[2] = tid*4+1; }
        if (S0 >= PRE_N && S1    < PRE_N) { scal[2] = tid*4+0; }
    }
    __syncthreads();
    const unsigned int bstar = scal[2];

    for (int j = tid; j < NA; j += 1024) {
        unsigned int u = __float_as_uint(objn[j]);
        unsigned int k = (u & 0x80000000u) ? ~u : (u | 0x80000000u);
        if ((k >> 20) < bstar) continue;
        int a = j / 10000, t = j - a * 10000;
        uint64_t key = (((uint64_t)(~k)) << 32) | (unsigned int)(t * 3 + a);
        unsigned int pos = atomicAdd(&scal[0], 1u);
        if (pos < CAND_MAX) candBuf[n * CAND_MAX + pos] = key;
    }
    __syncthreads();
    if (tid == 0) candCnt[n] = min(scal[0], (unsigned int)CAND_MAX);
}

// ---------------------------------------------------------------------------
// Kernel B (unchanged, verified R9): LDS-free wave-wide rank-by-counting.
// ---------------------------------------------------------------------------
__global__ __launch_bounds__(64) void rank_decode(
    const float* __restrict__ breg,
    const uint64_t* __restrict__ candBuf, const unsigned int* __restrict__ candCnt,
    float* __restrict__ wsBoxes, float* __restrict__ wsScores,
    int* __restrict__ wsValid)
{
    const int n    = blockIdx.x >> 6;
    const int tile = blockIdx.x & 63;
    const int lane = threadIdx.x;

    const int C = (int)candCnt[n];
    if (tile * 64 >= C) return;

    const uint64_t* cb = candBuf + n * CAND_MAX;
    const int my = tile * 64 + lane;
    const uint64_t km = (my < C) ? cb[my] : ~0ull;

    unsigned int rank = 0;
    const int nch = (C + 63) >> 6;
    for (int ch = 0; ch < nch; ++ch) {
        const int j = ch * 64 + lane;
        uint64_t ck = (j < C) ? cb[j] : ~0ull;
        unsigned int clo = (unsigned int)ck, chi = (unsigned int)(ck >> 32);
        #pragma unroll
        for (int c = 0; c < 64; ++c) {
            unsigned int lo = (unsigned int)__builtin_amdgcn_readlane((int)clo, c);
            unsigned int hi = (unsigned int)__builtin_amdgcn_readlane((int)chi, c);
            uint64_t kc = ((uint64_t)hi << 32) | lo;
            rank += (kc < km) ? 1u : 0u;
        }
    }
    if (my >= C || rank >= PRE_N) return;

    unsigned int idx = (unsigned int)km;
    unsigned int k   = ~((unsigned int)(km >> 32));
    unsigned int u   = (k & 0x80000000u) ? (k & 0x7fffffffu) : ~k;
    float logit = __uint_as_float(u);
    float score = 1.0f / (1.0f + expf(-logit));

    int a = idx % 3, t = idx / 3, w = t % 100, h = t / 100;
    const float* bp = breg + n*120000 + (a*4)*10000 + t;
    float dx = bp[0], dy = bp[10000], dw = bp[20000], dh = bp[30000];

    float half = (a == 0) ? 32.0f : ((a == 1) ? 64.0f : 128.0f);
    float cx = w * 16.0f + 8.0f, cy = h * 16.0f + 8.0f;
    float x1 = cx - half, y1 = cy - half, x2 = cx + half, y2 = cy + half;
    float wd = x2 - x1 + 1.0f, hg = y2 - y1 + 1.0f;
    float cxr = x1 + 0.5f * wd, cyr = y1 + 0.5f * hg;
    dw = fminf(dw, DCLIP); dh = fminf(dh, DCLIP);
    float pcx = dx * wd + cxr, pcy = dy * hg + cyr;
    float pw = expf(dw) * wd, ph = expf(dh) * hg;
    float px1 = pcx - 0.5f * pw, py1 = pcy - 0.5f * ph;
    float px2 = pcx + 0.5f * pw - 1.0f, py2 = pcy + 0.5f * ph - 1.0f;
    px1 = fminf(fmaxf(px1, 0.0f), IMGM1);
    px2 = fminf(fmaxf(px2, 0.0f), IMGM1);
    py1 = fminf(fmaxf(py1, 0.0f), IMGM1);
    py2 = fminf(fmaxf(py2, 0.0f), IMGM1);
    float wss = px2 - px1 + 1.0f, hss = py2 - py1 + 1.0f;
    float xc = px1 + wss * 0.5f, yc = py1 + hss * 0.5f;
    int valid = (wss >= 0.0f) && (hss >= 0.0f) && (xc < IMGF) && (yc < IMGF);

    ((float4*)wsBoxes)[n * PRE_N + (int)rank] = make_float4(px1, py1, px2, py2);
    wsScores[n * PRE_N + (int)rank] = score;
    wsValid [n * PRE_N + (int)rank] = valid;
}

// ---------------------------------------------------------------------------
// Verified inline-asm scan macros (R8): 64-slot VGPR ring, pure-SALU chain,
// early-exit at kept=1000.
// ---------------------------------------------------------------------------
#define SL(n,b) \
    "global_load_dword v" #n ", %[voff], %[sbase]\n\t" \
    "v_add_u32 %[voff], 0x100, %[voff]\n\t"

#define SS(n,b) \
    "s_waitcnt vmcnt(63)\n\t" \
    "v_readlane_b32 %[t], v" #n ", %[lw]\n\t" \
    "s_bitcmp1_b32 %[win], " #b "\n\t" \
    "s_cselect_b32 %[m], 0, -1\n\t" \
    "s_sub_i32 %[kept], %[kept], %[m]\n\t" \
    "s_and_b32 %[t], %[t], %[m]\n\t" \
    "s_or_b32 %[win], %[win], %[t]\n\t" \
    "v_and_b32 v" #n ", %[m], v" #n "\n\t" \
    "v_or_b32 %[rem], %[rem], v" #n "\n\t" \
    "global_load_dword v" #n ", %[voff], %[sbase]\n\t" \
    "v_add_u32 %[voff], 0x100, %[voff]\n\t"

#define SN(n,b,w) \
    "s_waitcnt vmcnt(" #w ")\n\t" \
    "v_readlane_b32 %[t], v" #n ", %[lw]\n\t" \
    "s_bitcmp1_b32 %[win], " #b "\n\t" \
    "s_cselect_b32 %[m], 0, -1\n\t" \
    "s_sub_i32 %[kept], %[kept], %[m]\n\t" \
    "s_and_b32 %[t], %[t], %[m]\n\t" \
    "s_or_b32 %[win], %[win], %[t]\n\t" \
    "v_and_b32 v" #n ", %[m], v" #n "\n\t" \
    "v_or_b32 %[rem], %[rem], v" #n "\n\t"

#define SWIN \
    "s_add_u32 %[lw], %[lw], 1\n\t" \
    "v_readlane_b32 %[t], %[rem], %[lw]\n\t" \
    "s_mov_b32 %[win], %[t]\n\t"

#define ROW_A(M) M(64,0) M(65,1) M(66,2) M(67,3) M(68,4) M(69,5) M(70,6) M(71,7) \
    M(72,8) M(73,9) M(74,10) M(75,11) M(76,12) M(77,13) M(78,14) M(79,15) \
    M(80,16) M(81,17) M(82,18) M(83,19) M(84,20) M(85,21) M(86,22) M(87,23) \
    M(88,24) M(89,25) M(90,26) M(91,27) M(92,28) M(93,29) M(94,30) M(95,31)
#define ROW_B(M) M(96,0) M(97,1) M(98,2) M(99,3) M(100,4) M(101,5) M(102,6) M(103,7) \
    M(104,8) M(105,9) M(106,10) M(107,11) M(108,12) M(109,13) M(110,14) M(111,15) \
    M(112,16) M(113,17) M(114,18) M(115,19) M(116,20) M(117,21) M(118,22) M(119,23) \
    M(120,24) M(121,25) M(122,26) M(123,27) M(124,28) M(125,29) M(126,30) M(127,31)

// ---------------------------------------------------------------------------
// Kernel C (R13): mask (verified R11, div-free + LDS-staged store) FUSED with
// scan (verified R12 512-thr) via last-block-done: each image's 32 mask blocks
// release-fence + atomicAdd(done[n]); the 32nd runs scan+select for image n.
// Removes one graph node and overlaps scan with other images' mask work.
// ---------------------------------------------------------------------------
__global__ __launch_bounds__(512) void nms_mask_scan(
    const float* __restrict__ wsBoxes, const float* __restrict__ wsScores,
    const int* __restrict__ wsValid, uint64_t* __restrict__ mask,
    unsigned int* __restrict__ doneArr, float* __restrict__ out)
{
    const int blk  = blockIdx.x;
    const int n    = blk >> 5;
    const int i_t  = blk & 31;
    const int tid  = threadIdx.x;
    const int lane = tid & 63;
    const int wv   = tid >> 6;   // 0..7

    __shared__ uint64_t tile[64 * 33];
    __shared__ int sScan[512];
    __shared__ __align__(8) unsigned char sInvb[256];
    __shared__ unsigned int sKeep[64];
    __shared__ unsigned int sFlag;

    // ---- mask phase (bit-identical to R11) ----
    for (int idx = tid; idx < 64 * 33; idx += 512) tile[idx] = 0ull;
    __syncthreads();

    const int r = i_t * 64 + lane;
    float4 rb = (r < PRE_N) ? ((const float4*)wsBoxes)[n * PRE_N + r]
                            : make_float4(0.f, 0.f, 0.f, 0.f);
    float ra = (rb.z - rb.x + 1.0f) * (rb.w - rb.y + 1.0f);

    for (int j_t = i_t + wv; j_t < 32; j_t += 8) {
        const int j = j_t * 64 + lane;
        float4 cb = (j < PRE_N) ? ((const float4*)wsBoxes)[n * PRE_N + j]
                                : make_float4(3e30f, 3e30f, 3e30f, 3e30f);
        float ca = (cb.z - cb.x + 1.0f) * (cb.w - cb.y + 1.0f);
        const uint64_t jmask = (j_t == 31) ? 0xFFFFull : ~0ull;
        const bool diag = (j_t == i_t);
        uint64_t myword = 0ull;

        #pragma unroll
        for (int c = 0; c < 64; ++c) {
            float rx1 = __int_as_float(__builtin_amdgcn_readlane(__float_as_int(rb.x), c));
            float ry1 = __int_as_float(__builtin_amdgcn_readlane(__float_as_int(rb.y), c));
            float rx2 = __int_as_float(__builtin_amdgcn_readlane(__float_as_int(rb.z), c));
            float ry2 = __int_as_float(__builtin_amdgcn_readlane(__float_as_int(rb.w), c));
            float rar = __int_as_float(__builtin_amdgcn_readlane(__float_as_int(ra), c));
            float xx1 = fmaxf(rx1, cb.x), yy1 = fmaxf(ry1, cb.y);
            float xx2 = fminf(rx2, cb.z), yy2 = fminf(ry2, cb.w);
            float ww = fmaxf(xx2 - xx1 + 1.0f, 0.0f);
            float hh = fmaxf(yy2 - yy1 + 1.0f, 0.0f);
            float inter = ww * hh;
            float denom = rar + ca - inter;
            unsigned long long bits = __ballot(inter > NMS_TH * denom) & jmask;
            if (diag) bits &= (c == 63) ? 0ull : ((~0ull) << (c + 1));
            if (lane == c) myword = bits;
        }
        tile[lane * 33 + j_t] = myword;
    }
    __syncthreads();

    uint64_t* mrow = mask + ((size_t)n * PRE_N + (size_t)i_t * 64) * 32;
    const int cmax = (i_t == 31) ? 16 : 64;
    for (int idx = tid; idx < cmax * 32; idx += 512) {
        const int rr = idx >> 5, w = idx & 31;
        mrow[idx] = tile[rr * 33 + w];
    }
    __syncthreads();   // each wave drains vmcnt(0) before barrier -> stores in L2

    // ---- last-block-done handoff ----
    if (tid == 0) {
        __threadfence();                       // release: writeback dirty L2
        sFlag = atomicAdd(&doneArr[n], 1u);    // device-scope
    }
    __syncthreads();
    if (sFlag != 31u) return;                  // not the last block of image n
    __threadfence();                           // acquire: invalidate caches

    // ---- scan + select phase (verified R12 512-thread version) ----
    if (tid < 256) {
        unsigned int byte = 0xFFu;
        if (tid < PRE_N / 8) {
            byte = 0u;
            for (int q = 0; q < 8; ++q)
                byte |= (wsValid[n * PRE_N + tid * 8 + q] ? 0u : 1u) << q;
        }
        sInvb[tid] = (unsigned char)byte;
    }
    __syncthreads();

    if (tid < 64) {
        unsigned int rem = ((const unsigned int*)sInvb)[tid];
        unsigned long long sbase =
            (unsigned long long)(const void*)(mask + (size_t)n * PRE_N * 32);
        unsigned int voff = (unsigned int)(tid * 4);
        int win_, m_, t_, lw_, kept_, cnt_;

        asm volatile(
            "s_waitcnt vmcnt(0) lgkmcnt(0)\n\t"
            "s_mov_b32 %[kept], 0\n\t"
            "s_mov_b32 %[lw], 0\n\t"
            ROW_A(SL) ROW_B(SL)
            "v_readlane_b32 %[t], %[rem], %[lw]\n\t"
            "s_mov_b32 %[win], %[t]\n\t"
            "s_mov_b32 %[cnt], 30\n\t"
            "Lnms_%=:\n\t"
            ROW_A(SS)
            SWIN
            ROW_B(SS)
            SWIN
            "s_cmp_ge_i32 %[kept], 0x3e8\n\t"
            "s_cbranch_scc1 Lend_%=\n\t"
            "s_sub_u32 %[cnt], %[cnt], 1\n\t"
            "s_cmp_lg_u32 %[cnt], 0\n\t"
            "s_cbranch_scc1 Lnms_%=\n\t"
            SS(64,0) SS(65,1) SS(66,2) SS(67,3) SS(68,4) SS(69,5) SS(70,6) SS(71,7)
            SS(72,8) SS(73,9) SS(74,10) SS(75,11) SS(76,12) SS(77,13) SS(78,14) SS(79,15)
            SN(80,16,63) SN(81,17,62) SN(82,18,61) SN(83,19,60)
            SN(84,20,59) SN(85,21,58) SN(86,22,57) SN(87,23,56)
            SN(88,24,55) SN(89,25,54) SN(90,26,53) SN(91,27,52)
            SN(92,28,51) SN(93,29,50) SN(94,30,49) SN(95,31,48)
            SWIN
            SN(96,0,47) SN(97,1,46) SN(98,2,45) SN(99,3,44)
            SN(100,4,43) SN(101,5,42) SN(102,6,41) SN(103,7,40)
            SN(104,8,39) SN(105,9,38) SN(106,10,37) SN(107,11,36)
            SN(108,12,35) SN(109,13,34) SN(110,14,33) SN(111,15,32)
            SN(112,16,31) SN(113,17,30) SN(114,18,29) SN(115,19,28)
            SN(116,20,27) SN(117,21,26) SN(118,22,25) SN(119,23,24)
            SN(120,24,23) SN(121,25,22) SN(122,26,21) SN(123,27,20)
            SN(124,28,19) SN(125,29,18) SN(126,30,17) SN(127,31,16)
            SWIN
            SN(64,0,15) SN(65,1,14) SN(66,2,13) SN(67,3,12)
            SN(68,4,11) SN(69,5,10) SN(70,6,9) SN(71,7,8)
            SN(72,8,7) SN(73,9,6) SN(74,10,5) SN(75,11,4)
            SN(76,12,3) SN(77,13,2) SN(78,14,1) SN(79,15,0)
            "Lend_%=:\n\t"
            "s_waitcnt vmcnt(0)\n\t"
            : [rem]"+v"(rem), [voff]"+v"(voff),
              [win]"=&s"(win_), [m]"=&s"(m_), [t]"=&s"(t_),
              [lw]"=&s"(lw_), [kept]"=&s"(kept_), [cnt]"=&s"(cnt_)
            : [sbase]"s"(sbase)
            : "scc", "vcc", "memory",
              "v64","v65","v66","v67","v68","v69","v70","v71",
              "v72","v73","v74","v75","v76","v77","v78","v79",
              "v80","v81","v82","v83","v84","v85","v86","v87",
              "v88","v89","v90","v91","v92","v93","v94","v95",
              "v96","v97","v98","v99","v100","v101","v102","v103",
              "v104","v105","v106","v107","v108","v109","v110","v111",
              "v112","v113","v114","v115","v116","v117","v118","v119",
              "v120","v121","v122","v123","v124","v125","v126","v127");

        sKeep[tid] = ~rem;
    }
    __syncthreads();

    int cf[4]; const int base4 = tid * 4;
    int lsum = 0;
    for (int q = 0; q < 4; ++q) {
        const int i = base4 + q;
        cf[q] = (i < PRE_N) ? (int)((sKeep[i >> 5] >> (i & 31)) & 1u) : 0;
        lsum += cf[q];
    }
    sScan[tid] = lsum;
    __syncthreads();
    for (int off = 1; off < 512; off <<= 1) {
        int v = (tid >= off) ? sScan[tid - off] : 0;
        __syncthreads();
        sScan[tid] += v;
        __syncthreads();
    }
    const int excl  = sScan[tid] - lsum;
    const int total = sScan[511];

    float* ob  = out + n * POST_N * 4;
    float* osc = out + NIMG * POST_N * 4 + n * POST_N;
    float* ovd = out + NIMG * POST_N * 5 + n * POST_N;

    for (int i = tid; i < POST_N * 4; i += 512) ob[i] = 0.0f;
    for (int i = tid; i < POST_N; i += 512) osc[i] = 0.0f;
    const int lim = min(total, POST_N);
    for (int i = tid; i < POST_N; i += 512) ovd[i] = (i < lim) ? 1.0f : 0.0f;
    __syncthreads();

    int run = excl;
    for (int q = 0; q < 4; ++q) {
        const int i = base4 + q;
        if (i < PRE_N && cf[q]) {
            if (run < POST_N) {
                float4 b = ((const float4*)wsBoxes)[n * PRE_N + i];
                ob[run * 4 + 0] = b.x;
                ob[run * 4 + 1] = b.y;
                ob[run * 4 + 2] = b.z;
                ob[run * 4 + 3] = b.w;
                osc[run] = wsScores[n * PRE_N + i];
            }
            run++;
        }
    }
}

extern "C" void kernel_launch(void* const* d_in, const int* in_sizes, int n_in,
                              void* d_out, int out_size, void* d_ws, size_t ws_size,
                              hipStream_t stream) {
    const float* obj  = (const float*)d_in[0];
    const float* breg = (const float*)d_in[1];
    // d_in[2] anchors unused (computed inline, exact in f32)
    float* ws        = (float*)d_ws;
    float* wsBoxes   = ws;                      // 64000 floats
    float* wsScores  = ws + 64000;              // 16000 floats
    int*   wsValid   = (int*)(ws + 80000);      // 16000 ints
    uint64_t* wsMask = (uint64_t*)(ws + 96000); // 8*2000*32 u64 = 4.096 MB
    uint64_t*     candBuf = wsMask;             // alias (dead before mask writes)
    unsigned int* candCnt = (unsigned int*)(wsMask + NIMG * CAND_MAX);
    unsigned int* doneArr =
        (unsigned int*)((char*)wsMask + (size_t)NIMG * PRE_N * 32 * 8); // past mask

    hist_compact<<<NIMG, 1024, 0, stream>>>(obj, candBuf, candCnt, doneArr);
    rank_decode<<<NIMG * 64, 64, 0, stream>>>(breg, candBuf, candCnt,
                                              wsBoxes, wsScores, wsValid);
    nms_mask_scan<<<NIMG * 32, 512, 0, stream>>>(wsBoxes, wsScores, wsValid,
                                                 wsMask, doneArr, (float*)d_out);
}

// Round 14
// 183.978 us; speedup vs baseline: 3.2044x; 1.0375x over previous
//
#include <hip/hip_runtime.h>
#include <math.h>
#include <stdint.h>

#define NIMG   8
#define NA     30000      // H*W*A = 100*100*3
#define PRE_N  2000
#define POST_N 1000
#define NMS_TH 0.7f
#define DCLIP  4.135166556742356f   // log(1000/16)
#define IMGF   1600.0f
#define IMGM1  1599.0f
#define CAND_MAX 4096

// ws layout (floats): boxes [8][2000][4] @0, scores [8][2000] @64000,
//   valid(int) [8][2000] @80000, mask(u64) [8][2000][32] @96000.
// candBuf (u64 [8][4096]) + candCnt alias the START of the mask region
// (dead until nms_mask runs; same stream => safe).

// ---------------------------------------------------------------------------
// Kernel A (verified): histogram + boundary bin + compact.
// ---------------------------------------------------------------------------
__global__ __launch_bounds__(1024) void hist_compact(
    const float* __restrict__ obj,
    uint64_t* __restrict__ candBuf, unsigned int* __restrict__ candCnt)
{
    const int n    = blockIdx.x;
    const int tid  = threadIdx.x;
    const int lane = tid & 63;
    const int wid  = tid >> 6;

    __shared__ unsigned int hist[4096];
    __shared__ unsigned int wsum[16];
    __shared__ unsigned int scal[4];

    for (int b = tid; b < 4096; b += 1024) hist[b] = 0u;
    if (tid < 4) scal[tid] = 0u;
    __syncthreads();

    const float* objn = obj + n * NA;

    for (int j = tid; j < NA; j += 1024) {
        unsigned int u = __float_as_uint(objn[j]);
        unsigned int k = (u & 0x80000000u) ? ~u : (u | 0x80000000u);
        atomicAdd(&hist[k >> 20], 1u);
    }
    __syncthreads();

    unsigned int c0 = hist[tid*4+0], c1 = hist[tid*4+1],
                 c2 = hist[tid*4+2], c3 = hist[tid*4+3];
    unsigned int p = c0 + c1 + c2 + c3;
    unsigned int s = p;
    #pragma unroll
    for (int off = 1; off < 64; off <<= 1) {
        unsigned int v = __shfl_down(s, off);
        if (lane + off < 64) s += v;
    }
    if (lane == 0) wsum[wid] = s;
    __syncthreads();
    unsigned int wafter = 0;
    for (int w = wid + 1; w < 16; ++w) wafter += wsum[w];
    unsigned int after = (s - p) + wafter;
    {
        unsigned int S3 = after + c3;
        unsigned int S2 = S3 + c2;
        unsigned int S1 = S2 + c1;
        unsigned int S0 = S1 + c0;
        if (S3 >= PRE_N && after < PRE_N) { scal[2] = tid*4+3; }
        if (S2 >= PRE_N && S3    < PRE_N) { scal[2] = tid*4+2; }
        if (S1 >= PRE_N && S2    < PRE_N) { scal[2] = tid*4+1; }
        if (S0 >= PRE_N && S1    < PRE_N) { scal[2] = tid*4+0; }
    }
    __syncthreads();
    const unsigned int bstar = scal[2];

    for (int j = tid; j < NA; j += 1024) {
        unsigned int u = __float_as_uint(objn[j]);
        unsigned int k = (u & 0x80000000u) ? ~u : (u | 0x80000000u);
        if ((k >> 20) < bstar) continue;
        int a = j / 10000, t = j - a * 10000;
        uint64_t key = (((uint64_t)(~k)) << 32) | (unsigned int)(t * 3 + a);
        unsigned int pos = atomicAdd(&scal[0], 1u);
        if (pos < CAND_MAX) candBuf[n * CAND_MAX + pos] = key;
    }
    __syncthreads();
    if (tid == 0) candCnt[n] = min(scal[0], (unsigned int)CAND_MAX);
}

// ---------------------------------------------------------------------------
// Kernel B (verified R9): LDS-free wave-wide rank-by-counting + decode.
// ---------------------------------------------------------------------------
__global__ __launch_bounds__(64) void rank_decode(
    const float* __restrict__ breg,
    const uint64_t* __restrict__ candBuf, const unsigned int* __restrict__ candCnt,
    float* __restrict__ wsBoxes, float* __restrict__ wsScores,
    int* __restrict__ wsValid)
{
    const int n    = blockIdx.x >> 6;
    const int tile = blockIdx.x & 63;
    const int lane = threadIdx.x;

    const int C = (int)candCnt[n];
    if (tile * 64 >= C) return;

    const uint64_t* cb = candBuf + n * CAND_MAX;
    const int my = tile * 64 + lane;
    const uint64_t km = (my < C) ? cb[my] : ~0ull;

    unsigned int rank = 0;
    const int nch = (C + 63) >> 6;
    for (int ch = 0; ch < nch; ++ch) {
        const int j = ch * 64 + lane;
        uint64_t ck = (j < C) ? cb[j] : ~0ull;
        unsigned int clo = (unsigned int)ck, chi = (unsigned int)(ck >> 32);
        #pragma unroll
        for (int c = 0; c < 64; ++c) {
            unsigned int lo = (unsigned int)__builtin_amdgcn_readlane((int)clo, c);
            unsigned int hi = (unsigned int)__builtin_amdgcn_readlane((int)chi, c);
            uint64_t kc = ((uint64_t)hi << 32) | lo;
            rank += (kc < km) ? 1u : 0u;
        }
    }
    if (my >= C || rank >= PRE_N) return;

    unsigned int idx = (unsigned int)km;
    unsigned int k   = ~((unsigned int)(km >> 32));
    unsigned int u   = (k & 0x80000000u) ? (k & 0x7fffffffu) : ~k;
    float logit = __uint_as_float(u);
    float score = 1.0f / (1.0f + expf(-logit));

    int a = idx % 3, t = idx / 3, w = t % 100, h = t / 100;
    const float* bp = breg + n*120000 + (a*4)*10000 + t;
    float dx = bp[0], dy = bp[10000], dw = bp[20000], dh = bp[30000];

    float half = (a == 0) ? 32.0f : ((a == 1) ? 64.0f : 128.0f);
    float cx = w * 16.0f + 8.0f, cy = h * 16.0f + 8.0f;
    float x1 = cx - half, y1 = cy - half, x2 = cx + half, y2 = cy + half;
    float wd = x2 - x1 + 1.0f, hg = y2 - y1 + 1.0f;
    float cxr = x1 + 0.5f * wd, cyr = y1 + 0.5f * hg;
    dw = fminf(dw, DCLIP); dh = fminf(dh, DCLIP);
    float pcx = dx * wd + cxr, pcy = dy * hg + cyr;
    float pw = expf(dw) * wd, ph = expf(dh) * hg;
    float px1 = pcx - 0.5f * pw, py1 = pcy - 0.5f * ph;
    float px2 = pcx + 0.5f * pw - 1.0f, py2 = pcy + 0.5f * ph - 1.0f;
    px1 = fminf(fmaxf(px1, 0.0f), IMGM1);
    px2 = fminf(fmaxf(px2, 0.0f), IMGM1);
    py1 = fminf(fmaxf(py1, 0.0f), IMGM1);
    py2 = fminf(fmaxf(py2, 0.0f), IMGM1);
    float wss = px2 - px1 + 1.0f, hss = py2 - py1 + 1.0f;
    float xc = px1 + wss * 0.5f, yc = py1 + hss * 0.5f;
    int valid = (wss >= 0.0f) && (hss >= 0.0f) && (xc < IMGF) && (yc < IMGF);

    ((float4*)wsBoxes)[n * PRE_N + (int)rank] = make_float4(px1, py1, px2, py2);
    wsScores[n * PRE_N + (int)rank] = score;
    wsValid [n * PRE_N + (int)rank] = valid;
}

// ---------------------------------------------------------------------------
// Kernel C (verified R11): div-free IoU predicate (inter > TH*denom), ballot
// mask word, LDS-staged contiguous store. One block (8 waves) per row-tile.
// ---------------------------------------------------------------------------
__global__ __launch_bounds__(512) void nms_mask(
    const float* __restrict__ wsBoxes, uint64_t* __restrict__ mask)
{
    const int blk  = blockIdx.x;
    const int n    = blk >> 5;
    const int i_t  = blk & 31;
    const int tid  = threadIdx.x;
    const int lane = tid & 63;
    const int wv   = tid >> 6;   // 0..7

    __shared__ uint64_t tile[64 * 33];   // padded pitch 33

    for (int idx = tid; idx < 64 * 33; idx += 512) tile[idx] = 0ull;
    __syncthreads();

    const int r = i_t * 64 + lane;
    float4 rb = (r < PRE_N) ? ((const float4*)wsBoxes)[n * PRE_N + r]
                            : make_float4(0.f, 0.f, 0.f, 0.f);
    float ra = (rb.z - rb.x + 1.0f) * (rb.w - rb.y + 1.0f);

    for (int j_t = i_t + wv; j_t < 32; j_t += 8) {
        const int j = j_t * 64 + lane;
        float4 cb = (j < PRE_N) ? ((const float4*)wsBoxes)[n * PRE_N + j]
                                : make_float4(3e30f, 3e30f, 3e30f, 3e30f);
        float ca = (cb.z - cb.x + 1.0f) * (cb.w - cb.y + 1.0f);
        const uint64_t jmask = (j_t == 31) ? 0xFFFFull : ~0ull;
        const bool diag = (j_t == i_t);
        uint64_t myword = 0ull;

        #pragma unroll
        for (int c = 0; c < 64; ++c) {
            float rx1 = __int_as_float(__builtin_amdgcn_readlane(__float_as_int(rb.x), c));
            float ry1 = __int_as_float(__builtin_amdgcn_readlane(__float_as_int(rb.y), c));
            float rx2 = __int_as_float(__builtin_amdgcn_readlane(__float_as_int(rb.z), c));
            float ry2 = __int_as_float(__builtin_amdgcn_readlane(__float_as_int(rb.w), c));
            float rar = __int_as_float(__builtin_amdgcn_readlane(__float_as_int(ra), c));
            float xx1 = fmaxf(rx1, cb.x), yy1 = fmaxf(ry1, cb.y);
            float xx2 = fminf(rx2, cb.z), yy2 = fminf(ry2, cb.w);
            float ww = fmaxf(xx2 - xx1 + 1.0f, 0.0f);
            float hh = fmaxf(yy2 - yy1 + 1.0f, 0.0f);
            float inter = ww * hh;
            float denom = rar + ca - inter;
            unsigned long long bits = __ballot(inter > NMS_TH * denom) & jmask;
            if (diag) bits &= (c == 63) ? 0ull : ((~0ull) << (c + 1));
            if (lane == c) myword = bits;
        }
        tile[lane * 33 + j_t] = myword;
    }
    __syncthreads();

    uint64_t* mrow = mask + ((size_t)n * PRE_N + (size_t)i_t * 64) * 32;
    const int cmax = (i_t == 31) ? 16 : 64;
    for (int idx = tid; idx < cmax * 32; idx += 512) {
        const int rr = idx >> 5, w = idx & 31;
        mrow[idx] = tile[rr * 33 + w];
    }
}

// ---------------------------------------------------------------------------
// Kernel D (verified R8): serial greedy scan, inline asm, 64-slot VGPR ring,
// pure-SALU chain, early-exit at kept=1000.
// ---------------------------------------------------------------------------
#define SL(n,b) \
    "global_load_dword v" #n ", %[voff], %[sbase]\n\t" \
    "v_add_u32 %[voff], 0x100, %[voff]\n\t"

#define SS(n,b) \
    "s_waitcnt vmcnt(63)\n\t" \
    "v_readlane_b32 %[t], v" #n ", %[lw]\n\t" \
    "s_bitcmp1_b32 %[win], " #b "\n\t" \
    "s_cselect_b32 %[m], 0, -1\n\t" \
    "s_sub_i32 %[kept], %[kept], %[m]\n\t" \
    "s_and_b32 %[t], %[t], %[m]\n\t" \
    "s_or_b32 %[win], %[win], %[t]\n\t" \
    "v_and_b32 v" #n ", %[m], v" #n "\n\t" \
    "v_or_b32 %[rem], %[rem], v" #n "\n\t" \
    "global_load_dword v" #n ", %[voff], %[sbase]\n\t" \
    "v_add_u32 %[voff], 0x100, %[voff]\n\t"

#define SN(n,b,w) \
    "s_waitcnt vmcnt(" #w ")\n\t" \
    "v_readlane_b32 %[t], v" #n ", %[lw]\n\t" \
    "s_bitcmp1_b32 %[win], " #b "\n\t" \
    "s_cselect_b32 %[m], 0, -1\n\t" \
    "s_sub_i32 %[kept], %[kept], %[m]\n\t" \
    "s_and_b32 %[t], %[t], %[m]\n\t" \
    "s_or_b32 %[win], %[win], %[t]\n\t" \
    "v_and_b32 v" #n ", %[m], v" #n "\n\t" \
    "v_or_b32 %[rem], %[rem], v" #n "\n\t"

#define SWIN \
    "s_add_u32 %[lw], %[lw], 1\n\t" \
    "v_readlane_b32 %[t], %[rem], %[lw]\n\t" \
    "s_mov_b32 %[win], %[t]\n\t"

#define ROW_A(M) M(64,0) M(65,1) M(66,2) M(67,3) M(68,4) M(69,5) M(70,6) M(71,7) \
    M(72,8) M(73,9) M(74,10) M(75,11) M(76,12) M(77,13) M(78,14) M(79,15) \
    M(80,16) M(81,17) M(82,18) M(83,19) M(84,20) M(85,21) M(86,22) M(87,23) \
    M(88,24) M(89,25) M(90,26) M(91,27) M(92,28) M(93,29) M(94,30) M(95,31)
#define ROW_B(M) M(96,0) M(97,1) M(98,2) M(99,3) M(100,4) M(101,5) M(102,6) M(103,7) \
    M(104,8) M(105,9) M(106,10) M(107,11) M(108,12) M(109,13) M(110,14) M(111,15) \
    M(112,16) M(113,17) M(114,18) M(115,19) M(116,20) M(117,21) M(118,22) M(119,23) \
    M(120,24) M(121,25) M(122,26) M(123,27) M(124,28) M(125,29) M(126,30) M(127,31)

__global__ __launch_bounds__(256) void nms_scan_select(
    const float* __restrict__ wsBoxes, const float* __restrict__ wsScores,
    const int* __restrict__ wsValid, const uint64_t* __restrict__ mask,
    float* __restrict__ out)
{
    const int n   = blockIdx.x;
    const int tid = threadIdx.x;

    __shared__ __align__(8) unsigned char invb[256];
    __shared__ unsigned int keepw32[64];
    __shared__ int sscan[256];

    unsigned int byte = 0xFFu;
    if (tid < PRE_N / 8) {
        byte = 0u;
        for (int q = 0; q < 8; ++q)
            byte |= (wsValid[n * PRE_N + tid * 8 + q] ? 0u : 1u) << q;
    }
    invb[tid] = (unsigned char)byte;
    __syncthreads();

    if (tid < 64) {
        unsigned int rem = ((const unsigned int*)invb)[tid];
        unsigned long long sbase =
            (unsigned long long)(const void*)(mask + (size_t)n * PRE_N * 32);
        unsigned int voff = (unsigned int)(tid * 4);
        int win_, m_, t_, lw_, kept_, cnt_;

        asm volatile(
            "s_waitcnt vmcnt(0) lgkmcnt(0)\n\t"
            "s_mov_b32 %[kept], 0\n\t"
            "s_mov_b32 %[lw], 0\n\t"
            ROW_A(SL) ROW_B(SL)
            "v_readlane_b32 %[t], %[rem], %[lw]\n\t"
            "s_mov_b32 %[win], %[t]\n\t"
            "s_mov_b32 %[cnt], 30\n\t"
            "Lnms_%=:\n\t"
            ROW_A(SS)
            SWIN
            ROW_B(SS)
            SWIN
            "s_cmp_ge_i32 %[kept], 0x3e8\n\t"
            "s_cbranch_scc1 Lend_%=\n\t"
            "s_sub_u32 %[cnt], %[cnt], 1\n\t"
            "s_cmp_lg_u32 %[cnt], 0\n\t"
            "s_cbranch_scc1 Lnms_%=\n\t"
            SS(64,0) SS(65,1) SS(66,2) SS(67,3) SS(68,4) SS(69,5) SS(70,6) SS(71,7)
            SS(72,8) SS(73,9) SS(74,10) SS(75,11) SS(76,12) SS(77,13) SS(78,14) SS(79,15)
            SN(80,16,63) SN(81,17,62) SN(82,18,61) SN(83,19,60)
            SN(84,20,59) SN(85,21,58) SN(86,22,57) SN(87,23,56)
            SN(88,24,55) SN(89,25,54) SN(90,26,53) SN(91,27,52)
            SN(92,28,51) SN(93,29,50) SN(94,30,49) SN(95,31,48)
            SWIN
            SN(96,0,47) SN(97,1,46) SN(98,2,45) SN(99,3,44)
            SN(100,4,43) SN(101,5,42) SN(102,6,41) SN(103,7,40)
            SN(104,8,39) SN(105,9,38) SN(106,10,37) SN(107,11,36)
            SN(108,12,35) SN(109,13,34) SN(110,14,33) SN(111,15,32)
            SN(112,16,31) SN(113,17,30) SN(114,18,29) SN(115,19,28)
            SN(116,20,27) SN(117,21,26) SN(118,22,25) SN(119,23,24)
            SN(120,24,23) SN(121,25,22) SN(122,26,21) SN(123,27,20)
            SN(124,28,19) SN(125,29,18) SN(126,30,17) SN(127,31,16)
            SWIN
            SN(64,0,15) SN(65,1,14) SN(66,2,13) SN(67,3,12)
            SN(68,4,11) SN(69,5,10) SN(70,6,9) SN(71,7,8)
            SN(72,8,7) SN(73,9,6) SN(74,10,5) SN(75,11,4)
            SN(76,12,3) SN(77,13,2) SN(78,14,1) SN(79,15,0)
            "Lend_%=:\n\t"
            "s_waitcnt vmcnt(0)\n\t"
            : [rem]"+v"(rem), [voff]"+v"(voff),
              [win]"=&s"(win_), [m]"=&s"(m_), [t]"=&s"(t_),
              [lw]"=&s"(lw_), [kept]"=&s"(kept_), [cnt]"=&s"(cnt_)
            : [sbase]"s"(sbase)
            : "scc", "vcc", "memory",
              "v64","v65","v66","v67","v68","v69","v70","v71",
              "v72","v73","v74","v75","v76","v77","v78","v79",
              "v80","v81","v82","v83","v84","v85","v86","v87",
              "v88","v89","v90","v91","v92","v93","v94","v95",
              "v96","v97","v98","v99","v100","v101","v102","v103",
              "v104","v105","v106","v107","v108","v109","v110","v111",
              "v112","v113","v114","v115","v116","v117","v118","v119",
              "v120","v121","v122","v123","v124","v125","v126","v127");

        keepw32[tid] = ~rem;
    }
    __syncthreads();

    int c[8]; const int base8 = tid * 8;
    int lsum = 0;
    for (int q = 0; q < 8; ++q) {
        const int i = base8 + q;
        c[q] = (i < PRE_N) ? (int)((keepw32[i >> 5] >> (i & 31)) & 1u) : 0;
        lsum += c[q];
    }
    sscan[tid] = lsum;
    __syncthreads();
    for (int off = 1; off < 256; off <<= 1) {
        int v = (tid >= off) ? sscan[tid - off] : 0;
        __syncthreads();
        sscan[tid] += v;
        __syncthreads();
    }
    const int excl  = sscan[tid] - lsum;
    const int total = sscan[255];

    float* ob  = out + n * POST_N * 4;
    float* osc = out + NIMG * POST_N * 4 + n * POST_N;
    float* ovd = out + NIMG * POST_N * 5 + n * POST_N;

    for (int i = tid; i < POST_N * 4; i += 256) ob[i] = 0.0f;
    for (int i = tid; i < POST_N; i += 256) osc[i] = 0.0f;
    const int lim = min(total, POST_N);
    for (int i = tid; i < POST_N; i += 256) ovd[i] = (i < lim) ? 1.0f : 0.0f;
    __syncthreads();

    int run = excl;
    for (int q = 0; q < 8; ++q) {
        const int i = base8 + q;
        if (i < PRE_N && c[q]) {
            if (run < POST_N) {
                float4 b = ((const float4*)wsBoxes)[n * PRE_N + i];
                ob[run * 4 + 0] = b.x;
                ob[run * 4 + 1] = b.y;
                ob[run * 4 + 2] = b.z;
                ob[run * 4 + 3] = b.w;
                osc[run] = wsScores[n * PRE_N + i];
            }
            run++;
        }
    }
}

extern "C" void kernel_launch(void* const* d_in, const int* in_sizes, int n_in,
                              void* d_out, int out_size, void* d_ws, size_t ws_size,
                              hipStream_t stream) {
    const float* obj  = (const float*)d_in[0];
    const float* breg = (const float*)d_in[1];
    // d_in[2] anchors unused (computed inline, exact in f32)
    float* ws        = (float*)d_ws;
    float* wsBoxes   = ws;                      // 64000 floats
    float* wsScores  = ws + 64000;              // 16000 floats
    int*   wsValid   = (int*)(ws + 80000);      // 16000 ints
    uint64_t* wsMask = (uint64_t*)(ws + 96000); // 8*2000*32 u64 = 4.096 MB
    uint64_t*     candBuf = wsMask;             // alias (dead before mask writes)
    unsigned int* candCnt = (unsigned int*)(wsMask + NIMG * CAND_MAX);

    hist_compact<<<NIMG, 1024, 0, stream>>>(obj, candBuf, candCnt);
    rank_decode<<<NIMG * 64, 64, 0, stream>>>(breg, candBuf, candCnt,
                                              wsBoxes, wsScores, wsValid);
    nms_mask<<<NIMG * 32, 512, 0, stream>>>(wsBoxes, wsMask);
    nms_scan_select<<<NIMG, 256, 0, stream>>>(wsBoxes, wsScores, wsValid, wsMask,
                                              (float*)d_out);
}